// Round 6
// baseline (325.425 us; speedup 1.0000x reference)
//
#include <hip/hip_runtime.h>
#include <cstdint>
#include <cstddef>
#include <math.h>

#define BN_   4
#define CC    96
#define C2    192
#define NN    3136
#define KNN   9
#define TILE  64
#define PT    8
#define FJR   580   /* 48*12 + 4 skew: keeps p/half broadcast groups on distinct bank quads */
#define WTS   100   /* transposed-weight LDS row stride: %4==0 (16B-aligned float4 rows) */

typedef __attribute__((ext_vector_type(8))) __bf16 bf16x8;
typedef __attribute__((ext_vector_type(4))) float f32x4;

__device__ __forceinline__ unsigned short f2bf(float f) {
  unsigned int u = __float_as_uint(f);
  unsigned int r = u + 0x7fffu + ((u >> 16) & 1u);   // RNE
  return (unsigned short)(r >> 16);
}
__device__ __forceinline__ float bf2f(unsigned short h) {
  return __uint_as_float(((unsigned int)h) << 16);
}
// monotone map: fmono(a) > fmono(b)  <=>  a > b  (as floats)
__device__ __forceinline__ unsigned int fmono(float f) {
  unsigned int s = __float_as_uint(f);
  return s ^ ((unsigned int)((int)s >> 31) | 0x80000000u);
}

// top-9 of u64 keys kept as a SORTED-DESCENDING list; insert-by-shift.
// key = (fmono(v)<<32) | ~idx  => value desc, idx asc (jax top_k tie-break).
// Keys are unique (col in low bits); real keys are always > 0; init = all 0.
// NOTE (r4 post-mortem): a branchless f32-value + parallel-col variant of
// this body compiled to ~5x the VALU instructions (108us -> 428us).  Keep
// the u64 single-array guarded form -- it is the measured-best codegen.
__device__ __forceinline__ void topk_ins(uint64_t key, uint64_t (&bk)[KNN]) {
  if (key > bk[KNN - 1]) {
    #pragma unroll
    for (int j = KNN - 1; j >= 1; --j) {
      bool aj   = bk[j]     > key;
      bool ajm1 = bk[j - 1] > key;
      bk[j] = aj ? bk[j] : (ajm1 ? key : bk[j - 1]);  // uses ORIGINAL bk[j-1]
    }
    bk[0] = (bk[0] > key) ? bk[0] : key;
  }
}

// ---------------------------------------------------------------------------
// K1: y1t[b][n][o] = bn1(fc1_w @ x + fc1_b).  n-major output for gathers.
// Weights staged to LDS TRANSPOSED (wT[c][o]) so the inner loop reads 6x
// float4 at a wave-uniform LDS address (broadcast) instead of 24 first-touch
// s_load_dword per c (scalar-cache thrash, ~200cy each, no TLP to hide it).
// ---------------------------------------------------------------------------
__global__ __launch_bounds__(256) void k_fc1(const float* __restrict__ x,
                                             const float* __restrict__ w,
                                             const float* __restrict__ bias,
                                             const float* __restrict__ bn,
                                             float* __restrict__ y1t) {
  __shared__ float xs[CC * 64];        // 24 KB, [c][64]
  __shared__ float wT[CC * WTS];       // 38.4 KB, wT[c*WTS + o]
  const int b = blockIdx.y, n0 = blockIdx.x * 64;
  const int t = threadIdx.x;
  for (int i = t; i < CC * 64; i += 256) {
    int c = i >> 6, nn = i & 63;
    xs[i] = x[((size_t)b * CC + c) * NN + n0 + nn];
  }
  for (int i = t; i < CC * CC; i += 256) {
    int o = i / CC, c = i % CC;        // w[o][c] row-major in global
    wT[c * WTS + o] = w[i];
  }
  __syncthreads();
  const int nn = t & 63;
  const int og = __builtin_amdgcn_readfirstlane(t >> 6);
  float acc[24];
  #pragma unroll
  for (int i = 0; i < 24; ++i) acc[i] = 0.f;
  for (int c = 0; c < CC; ++c) {
    float xv = xs[c * 64 + nn];
    const float* wp = &wT[c * WTS + og * 24];   // 16B-aligned (WTS%4==0, 24%4==0)
    float4 w0 = *(const float4*)(wp);
    float4 w1 = *(const float4*)(wp + 4);
    float4 w2 = *(const float4*)(wp + 8);
    float4 w3 = *(const float4*)(wp + 12);
    float4 w4 = *(const float4*)(wp + 16);
    float4 w5 = *(const float4*)(wp + 20);
    const float wv[24] = {w0.x, w0.y, w0.z, w0.w, w1.x, w1.y, w1.z, w1.w,
                          w2.x, w2.y, w2.z, w2.w, w3.x, w3.y, w3.z, w3.w,
                          w4.x, w4.y, w4.z, w4.w, w5.x, w5.y, w5.z, w5.w};
    #pragma unroll
    for (int oi = 0; oi < 24; ++oi) acc[oi] = fmaf(wv[oi], xv, acc[oi]);
  }
  #pragma unroll
  for (int oi = 0; oi < 24; ++oi) {
    int o = og * 24 + oi;
    float g = bn[o], be = bn[CC + o], mn = bn[2 * CC + o], vr = bn[3 * CC + o];
    float inv = g / sqrtf(vr + 1e-5f);
    float v = fmaf(acc[oi] + bias[o], inv, be - mn * inv);
    y1t[((size_t)b * NN + n0 + nn) * CC + o] = v;
  }
}

// ---------------------------------------------------------------------------
// K2: per-position L2 norm; emit bf16 split (hi, lo) of xn + sq.
// ---------------------------------------------------------------------------
__global__ __launch_bounds__(64) void k_norm(const float* __restrict__ y1t,
                                             unsigned short* __restrict__ xh,
                                             unsigned short* __restrict__ xl,
                                             float* __restrict__ sq) {
  const int p = blockIdx.x * 64 + threadIdx.x;  // 196*64 == 12544 exactly
  const float* row = y1t + (size_t)p * CC;
  float s = 0.f;
  for (int c = 0; c < CC; c += 4) {
    float4 v = *(const float4*)(row + c);
    s += v.x * v.x; s += v.y * v.y; s += v.z * v.z; s += v.w * v.w;
  }
  float inv = 1.f / fmaxf(sqrtf(s), 1e-12f);
  float sqs = 0.f;
  unsigned short* hrow = xh + (size_t)p * CC;
  unsigned short* lrow = xl + (size_t)p * CC;
  for (int c = 0; c < CC; c += 4) {
    float4 v4 = *(const float4*)(row + c);
    float v0 = v4.x * inv, v1 = v4.y * inv, v2 = v4.z * inv, v3 = v4.w * inv;
    // same accumulation order as the scalar loop -> bit-identical sq
    sqs += v0 * v0; sqs += v1 * v1; sqs += v2 * v2; sqs += v3 * v3;
    unsigned short h0 = f2bf(v0), h1 = f2bf(v1), h2 = f2bf(v2), h3 = f2bf(v3);
    float l0 = v0 - bf2f(h0), l1 = v1 - bf2f(h1), l2 = v2 - bf2f(h2), l3 = v3 - bf2f(h3);
    uint2 hv, lv;
    hv.x = (unsigned int)h0 | ((unsigned int)h1 << 16);
    hv.y = (unsigned int)h2 | ((unsigned int)h3 << 16);
    lv.x = (unsigned int)f2bf(l0) | ((unsigned int)f2bf(l1) << 16);
    lv.y = (unsigned int)f2bf(l2) | ((unsigned int)f2bf(l3) << 16);
    *(uint2*)&hrow[c] = hv;
    *(uint2*)&lrow[c] = lv;
  }
  sq[p] = sqs;
}

// ---------------------------------------------------------------------------
// K3: Gram via bf16-split MFMA with SWAPPED operands: mfma(bfrag, afrag)
// puts D-col = our Gram row, so each lane's accumulators all belong to ONE
// row (gr) and selection runs in registers.  Column chunks = gridDim.y.
// r3-exact internals (measured 107us).  Launched as TWO z=2 dispatches
// (boff 0/2) purely so the profiler's top-5 can surface other kernels.
// ---------------------------------------------------------------------------
__global__ __launch_bounds__(256) void k_dist(const unsigned short* __restrict__ xh,
                                              const unsigned short* __restrict__ xl,
                                              const float* __restrict__ sq,
                                              uint64_t* __restrict__ cand_k,
                                              int boff) {
  __shared__ __align__(16) unsigned short sB[2 * 64 * 104];  // 26624 B
  __shared__ __align__(16) float sqm[TILE];
  unsigned short* BsH = sB;
  unsigned short* BsL = sB + 64 * 104;

  const int rt = blockIdx.x, chunk = blockIdx.y, b = blockIdx.z + boff;
  const int nch = gridDim.y;
  const int r0 = rt * TILE;
  const int t = threadIdx.x;
  const int lane = t & 63, w = t >> 6;
  const int m16 = lane & 15, quad = lane >> 4;
  const int mt0 = (49 * chunk) / nch, mt1 = (49 * (chunk + 1)) / nch;

  // This lane's Gram row; A-fragments straight from global (once per block).
  const int gr = r0 + w * 16 + m16;
  bf16x8 ah[3], al[3];
  {
    const unsigned short* pH = xh + ((size_t)b * NN + gr) * CC + quad * 8;
    const unsigned short* pL = xl + ((size_t)b * NN + gr) * CC + quad * 8;
    #pragma unroll
    for (int kc = 0; kc < 3; ++kc) {
      ah[kc] = *(const bf16x8*)(pH + kc * 32);
      al[kc] = *(const bf16x8*)(pL + kc * 32);
    }
  }
  const float sr = sq[b * NN + gr];

  uint64_t bk[KNN];
  #pragma unroll
  for (int j = 0; j < KNN; ++j) bk[j] = 0ull;

  for (int mt = mt0; mt < mt1; ++mt) {
    const int m0 = mt * TILE;
    __syncthreads();  // prior tile's B-frag reads done before overwrite
    for (int i = t; i < 64 * 12; i += 256) {
      int r = i / 12, ch = i % 12;
      const uint4* sH = (const uint4*)(xh + ((size_t)b * NN + m0 + r) * CC);
      const uint4* sL = (const uint4*)(xl + ((size_t)b * NN + m0 + r) * CC);
      *(uint4*)&BsH[r * 104 + ch * 8] = sH[ch];
      *(uint4*)&BsL[r * 104 + ch * 8] = sL[ch];
    }
    if (t < TILE) sqm[t] = sq[b * NN + m0 + t];
    __syncthreads();

    #pragma unroll
    for (int tt = 0; tt < 4; ++tt) {
      const int brow = (tt * 16 + m16) * 104 + quad * 8;
      f32x4 acc = {0.f, 0.f, 0.f, 0.f};
      #pragma unroll
      for (int kc = 0; kc < 3; ++kc) {
        bf16x8 bh = *(const bf16x8*)&BsH[brow + kc * 32];
        bf16x8 bl = *(const bf16x8*)&BsL[brow + kc * 32];
        acc = __builtin_amdgcn_mfma_f32_16x16x32_bf16(bh, ah[kc], acc, 0, 0, 0);
        acc = __builtin_amdgcn_mfma_f32_16x16x32_bf16(bl, ah[kc], acc, 0, 0, 0);
        acc = __builtin_amdgcn_mfma_f32_16x16x32_bf16(bh, al[kc], acc, 0, 0, 0);
      }
      // lane's candidates: cols m0 + tt*16 + quad*4 + r, all for row gr
      float4 s4 = *(const float4*)&sqm[tt * 16 + quad * 4];  // broadcast read
      const float sv[4] = {s4.x, s4.y, s4.z, s4.w};
      #pragma unroll
      for (int r = 0; r < 4; ++r) {
        float v = 2.f * acc[r] - sr - sv[r];
        int col = m0 + tt * 16 + quad * 4 + r;
        uint64_t key = ((uint64_t)fmono(v) << 32) | (unsigned int)~col;
        topk_ins(key, bk);
      }
    }
  }
  __syncthreads();

  // merge the 4 per-quad lists of each row (scratch aliases sB)
  uint64_t* sk = (uint64_t*)sB;   // 64 rows * 4 quads * 9 * 8B = 18432 B
  #pragma unroll
  for (int j = 0; j < KNN; ++j) sk[((w * 16 + m16) * 4 + quad) * KNN + j] = bk[j];
  __syncthreads();
  if (t < TILE) {
    uint64_t fk[KNN];
    #pragma unroll
    for (int j = 0; j < KNN; ++j) fk[j] = 0ull;
    for (int qq = 0; qq < 4; ++qq)
      #pragma unroll
      for (int j = 0; j < KNN; ++j)
        topk_ins(sk[(t * 4 + qq) * KNN + j], fk);
    size_t base = (((size_t)b * nch + chunk) * NN + r0 + t) * KNN;
    #pragma unroll
    for (int j = 0; j < KNN; ++j) cand_k[base + j] = fk[j];
  }
}

// ---------------------------------------------------------------------------
// K4: merge nch chunk lists -> nn_idx (clamped to valid range).
// ---------------------------------------------------------------------------
__global__ __launch_bounds__(64) void k_nnmerge(const uint64_t* __restrict__ cand_k,
                                                int* __restrict__ nn_idx, int nch) {
  const int p = blockIdx.x * 64 + threadIdx.x;
  const int b = p / NN, n = p % NN;
  uint64_t fk[KNN];
  #pragma unroll
  for (int j = 0; j < KNN; ++j) fk[j] = 0ull;
  for (int ch = 0; ch < nch; ++ch) {
    size_t base = (((size_t)b * nch + ch) * NN + n) * KNN;
    #pragma unroll
    for (int j = 0; j < KNN; ++j) topk_ins(cand_k[base + j], fk);
  }
  #pragma unroll
  for (int j = 0; j < KNN; ++j) {
    int v = (int)(~(unsigned int)fk[j]);
    if ((unsigned)v >= (unsigned)NN) v = 0;  // sentinel guard: no wild gathers
    nn_idx[(size_t)p * KNN + j] = v;
  }
}

// ---------------------------------------------------------------------------
// K5: gather + grouped conv + bias + bn + relu + max over K.
// k-dep half remapped: half = l>>4 picks the db block, so each lane's f-rows
// are LDS-broadcast float4 reads (3 per c) instead of 9+ lane-variant reads.
// fj row span = FJR(580) floats: p/half groups land on distinct bank quads.
// ---------------------------------------------------------------------------
__global__ __launch_bounds__(256) void k_gconv(const float* __restrict__ y1t,
                                               const int* __restrict__ nn_idx,
                                               const float* __restrict__ gw,
                                               const float* __restrict__ gb,
                                               const float* __restrict__ bng,
                                               float* __restrict__ ymax) {
  __shared__ float wl[C2 * 49];
  __shared__ float xi[PT * CC];
  __shared__ __align__(16) float fj[PT * 2 * FJR];
  __shared__ int idxl[PT * KNN];
  const int t = threadIdx.x;
  const int p0 = blockIdx.x * PT;
  const int b0 = p0 / NN;

  for (int i = t; i < C2 * 48; i += 256) wl[(i / 48) * 49 + (i % 48)] = gw[i];
  if (t < PT * KNN) {
    int v = nn_idx[(size_t)p0 * KNN + t];
    idxl[t] = ((unsigned)v < (unsigned)NN) ? v : 0;
  }
  for (int i = t; i < PT * CC; i += 256) xi[i] = y1t[(size_t)p0 * CC + i];
  __syncthreads();

  for (int i = t; i < PT * KNN * CC; i += 256) {
    int pk = i / CC, c = i % CC;
    int p = pk / KNN, k = pk % KNN;
    int j = idxl[p * KNN + k];
    float v = y1t[((size_t)b0 * NN + j) * CC + c] - xi[p * CC + c];
    int h = (c >= 48) ? 1 : 0;
    fj[((p * 2 + h) * FJR) + (c - h * 48) * 12 + k] = v;
  }
  __syncthreads();

  const int p = t >> 5, l = t & 31;
  const size_t pg = p0 + p;
  float* orow = ymax + pg * C2;
  const float* xip = xi + p * CC;

  auto bnrelu = [&](int oc, float a) -> float {
    float g = bng[oc], be = bng[C2 + oc], mn = bng[2 * C2 + oc], vr = bng[3 * C2 + oc];
    float inv = g / sqrtf(vr + 1e-5f);
    return fmaxf(fmaf(a + gb[oc], inv, be - mn * inv), 0.f);
  };

  {  // k-free half
    const int oc0 = l, oc1 = l + 32, oc2 = l + 64;
    const int cb0 = (oc0 / 48) * 48, cb1 = (oc1 / 48) * 48, cb2 = (oc2 / 48) * 48;
    float a0 = 0.f, a1 = 0.f, a2 = 0.f;
    #pragma unroll 8
    for (int c = 0; c < 48; ++c) {
      a0 = fmaf(wl[oc0 * 49 + c], xip[cb0 + c], a0);
      a1 = fmaf(wl[oc1 * 49 + c], xip[cb1 + c], a1);
      a2 = fmaf(wl[oc2 * 49 + c], xip[cb2 + c], a2);
    }
    orow[oc0] = bnrelu(oc0, a0);
    orow[oc1] = bnrelu(oc1, a1);
    orow[oc2] = bnrelu(oc2, a2);
  }
  {  // k-dependent half (lane-remapped: uniform db per lane)
    const int half = l >> 4, lsub = l & 15;
    const int oc0 = 96 + half * 48 + lsub, oc1 = oc0 + 16, oc2 = oc0 + 32;
    const float* fbase = fj + ((size_t)p * 2 + half) * FJR;
    float acc0[KNN], acc1[KNN], acc2[KNN];
    #pragma unroll
    for (int k = 0; k < KNN; ++k) { acc0[k] = 0.f; acc1[k] = 0.f; acc2[k] = 0.f; }
    #pragma unroll 2
    for (int c = 0; c < 48; ++c) {
      float w0 = wl[oc0 * 49 + c], w1 = wl[oc1 * 49 + c], w2 = wl[oc2 * 49 + c];
      const float* fr = fbase + c * 12;
      float4 fA = *(const float4*)(fr);      // k 0..3 (16B-aligned: FJR*4%16==0)
      float4 fB = *(const float4*)(fr + 4);  // k 4..7
      float f8 = fr[8];
      const float fk[KNN] = {fA.x, fA.y, fA.z, fA.w, fB.x, fB.y, fB.z, fB.w, f8};
      #pragma unroll
      for (int k = 0; k < KNN; ++k) {
        acc0[k] = fmaf(w0, fk[k], acc0[k]);
        acc1[k] = fmaf(w1, fk[k], acc1[k]);
        acc2[k] = fmaf(w2, fk[k], acc2[k]);
      }
    }
    {
      float g = bng[oc0], be = bng[C2 + oc0], mn = bng[2 * C2 + oc0], vr = bng[3 * C2 + oc0];
      float inv = g / sqrtf(vr + 1e-5f), sh = be - mn * inv, bs = gb[oc0], m = 0.f;
      #pragma unroll
      for (int k = 0; k < KNN; ++k) m = fmaxf(m, fmaxf(fmaf(acc0[k] + bs, inv, sh), 0.f));
      orow[oc0] = m;
    }
    {
      float g = bng[oc1], be = bng[C2 + oc1], mn = bng[2 * C2 + oc1], vr = bng[3 * C2 + oc1];
      float inv = g / sqrtf(vr + 1e-5f), sh = be - mn * inv, bs = gb[oc1], m = 0.f;
      #pragma unroll
      for (int k = 0; k < KNN; ++k) m = fmaxf(m, fmaxf(fmaf(acc1[k] + bs, inv, sh), 0.f));
      orow[oc1] = m;
    }
    {
      float g = bng[oc2], be = bng[C2 + oc2], mn = bng[2 * C2 + oc2], vr = bng[3 * C2 + oc2];
      float inv = g / sqrtf(vr + 1e-5f), sh = be - mn * inv, bs = gb[oc2], m = 0.f;
      #pragma unroll
      for (int k = 0; k < KNN; ++k) m = fmaxf(m, fmaxf(fmaf(acc2[k] + bs, inv, sh), 0.f));
      orow[oc2] = m;
    }
  }
}

// ---------------------------------------------------------------------------
// K6: out = bn2(fc2_w @ ymax + fc2_b) + x
// w2 staged to LDS transposed (same rationale as K1): kills the 4608
// first-touch s_load_dword per wave.  LDS = 49.4 + 76.8 = 126 KB (gfx950
// has 160 KB/CU; 128 KB static precedent in learn_hip m201).
// ---------------------------------------------------------------------------
__global__ __launch_bounds__(256) void k_fc2(const float* __restrict__ ymax,
                                             const float* __restrict__ w2,
                                             const float* __restrict__ b2,
                                             const float* __restrict__ bn2,
                                             const float* __restrict__ xin,
                                             float* __restrict__ out) {
  __shared__ float ys[64 * 193];       // 49.4 KB
  __shared__ float w2T[C2 * WTS];      // 76.8 KB, w2T[c2*WTS + o]
  const int b = blockIdx.y, n0 = blockIdx.x * 64, t = threadIdx.x;
  for (int i = t; i < 64 * C2; i += 256) {
    int nn = i / C2, c2 = i % C2;
    ys[nn * 193 + c2] = ymax[((size_t)b * NN + n0 + nn) * C2 + c2];
  }
  for (int i = t; i < CC * C2; i += 256) {
    int o = i / C2, c2 = i % C2;       // w2[o][c2] row-major in global
    w2T[c2 * WTS + o] = w2[i];
  }
  __syncthreads();
  const int nn = t & 63;
  const int og = __builtin_amdgcn_readfirstlane(t >> 6);
  float acc[24];
  #pragma unroll
  for (int i = 0; i < 24; ++i) acc[i] = 0.f;
  const float* yrow = ys + nn * 193;
  for (int c2 = 0; c2 < C2; ++c2) {
    float yv = yrow[c2];
    const float* wp = &w2T[c2 * WTS + og * 24];  // 16B-aligned
    float4 w0 = *(const float4*)(wp);
    float4 w1 = *(const float4*)(wp + 4);
    float4 w2v = *(const float4*)(wp + 8);
    float4 w3 = *(const float4*)(wp + 12);
    float4 w4 = *(const float4*)(wp + 16);
    float4 w5 = *(const float4*)(wp + 20);
    const float wv[24] = {w0.x, w0.y, w0.z, w0.w, w1.x, w1.y, w1.z, w1.w,
                          w2v.x, w2v.y, w2v.z, w2v.w, w3.x, w3.y, w3.z, w3.w,
                          w4.x, w4.y, w4.z, w4.w, w5.x, w5.y, w5.z, w5.w};
    #pragma unroll
    for (int oi = 0; oi < 24; ++oi) acc[oi] = fmaf(wv[oi], yv, acc[oi]);
  }
  #pragma unroll
  for (int oi = 0; oi < 24; ++oi) {
    int o = og * 24 + oi;
    float g = bn2[o], be = bn2[CC + o], mn = bn2[2 * CC + o], vr = bn2[3 * CC + o];
    float inv = g / sqrtf(vr + 1e-5f);
    float v = fmaf(acc[oi] + b2[o], inv, be - mn * inv);
    size_t off = ((size_t)b * CC + o) * NN + n0 + nn;
    out[off] = v + xin[off];
  }
}

// ---------------------------------------------------------------------------
extern "C" void kernel_launch(void* const* d_in, const int* in_sizes, int n_in,
                              void* d_out, int out_size, void* d_ws, size_t ws_size,
                              hipStream_t stream) {
  const float* x     = (const float*)d_in[0];
  const float* fc1_w = (const float*)d_in[1];
  const float* fc1_b = (const float*)d_in[2];
  const float* bn1   = (const float*)d_in[3];
  const float* gc_w  = (const float*)d_in[4];
  const float* gc_b  = (const float*)d_in[5];
  const float* bng   = (const float*)d_in[6];
  const float* fc2_w = (const float*)d_in[7];
  const float* fc2_b = (const float*)d_in[8];
  const float* bn2   = (const float*)d_in[9];
  float* out = (float*)d_out;

  const size_t BNC = (size_t)BN_ * NN * CC;
  float* ws = (float*)d_ws;
  float* y1t = ws;                                   // B*N*C fp32
  unsigned short* xh = (unsigned short*)(y1t + BNC); // B*N*C bf16 hi
  unsigned short* xl = xh + BNC;                     // B*N*C bf16 lo
  float* sq     = ws + 2 * BNC;                      // B*N
  float* ymax   = sq + (size_t)BN_ * NN;             // B*N*C2 fp32
  int* nnidx = (int*)(ymax + (size_t)BN_ * NN * C2);

  // NCH=16 needs a dedicated cand_k region (14.45 MB) after nnidx; total
  // footprint 34.3 MB.  If ws is smaller, fall back to the verified NCH=8
  // layout with cand_k aliased onto ymax (7.2 MB <= 9.6 MB; cand_k is fully
  // consumed by k_nnmerge before k_gconv writes ymax -- single stream).
  const size_t base_bytes =
      (2 * BNC + (size_t)BN_ * NN + (size_t)BN_ * NN * C2) * 4 +
      (size_t)BN_ * NN * KNN * 4;                    // through nnidx
  const size_t need16 = base_bytes + (size_t)BN_ * 16 * NN * KNN * 8;
  int nch;
  uint64_t* cand_k;
  if (ws_size >= need16) {
    nch = 16;
    cand_k = (uint64_t*)((char*)d_ws + base_bytes);  // 8B-aligned (base%8==0)
  } else {
    nch = 8;
    cand_k = (uint64_t*)ymax;
  }

  k_fc1<<<dim3(NN / 64, BN_), 256, 0, stream>>>(x, fc1_w, fc1_b, bn1, y1t);
  k_norm<<<dim3((BN_ * NN) / 64), 64, 0, stream>>>(y1t, xh, xl, sq);
  // two half-batch dispatches (independent blocks; lets the profiler's
  // top-5 surface the next-biggest kernel instead of 5x k_dist@107us)
  k_dist<<<dim3(NN / TILE, nch, 2), 256, 0, stream>>>(xh, xl, sq, cand_k, 0);
  k_dist<<<dim3(NN / TILE, nch, 2), 256, 0, stream>>>(xh, xl, sq, cand_k, 2);
  k_nnmerge<<<dim3((BN_ * NN) / 64), 64, 0, stream>>>(cand_k, nnidx, nch);
  k_gconv<<<dim3((BN_ * NN) / PT), 256, 0, stream>>>(y1t, nnidx, gc_w, gc_b, bng, ymax);
  k_fc2<<<dim3(NN / 64, BN_), 256, 0, stream>>>(ymax, fc2_w, fc2_b, bn2, x, out);
}

// Round 7
// 299.376 us; speedup vs baseline: 1.0870x; 1.0870x over previous
//
#include <hip/hip_runtime.h>
#include <cstdint>
#include <cstddef>
#include <math.h>

#define BN_   4
#define CC    96
#define C2    192
#define NN    3136
#define KNN   9
#define TILE  64
#define PT    8
#define FJR   580   /* 48*12 + 4 skew: keeps p/half broadcast groups on distinct bank quads */
#define WTS   100   /* transposed-weight LDS row stride: %4==0 (16B-aligned float4 rows) */

typedef __attribute__((ext_vector_type(8))) __bf16 bf16x8;
typedef __attribute__((ext_vector_type(4))) float f32x4;

__device__ __forceinline__ unsigned short f2bf(float f) {
  unsigned int u = __float_as_uint(f);
  unsigned int r = u + 0x7fffu + ((u >> 16) & 1u);   // RNE
  return (unsigned short)(r >> 16);
}
__device__ __forceinline__ float bf2f(unsigned short h) {
  return __uint_as_float(((unsigned int)h) << 16);
}
// monotone map: fmono(a) > fmono(b)  <=>  a > b  (as floats)
__device__ __forceinline__ unsigned int fmono(float f) {
  unsigned int s = __float_as_uint(f);
  return s ^ ((unsigned int)((int)s >> 31) | 0x80000000u);
}

// top-9 of u64 keys kept as a SORTED-DESCENDING list; insert-by-shift.
// key = (fmono(v)<<32) | ~idx  => value desc, idx asc (jax top_k tie-break).
// Keys are unique (col in low bits); real keys are always > 0; init = all 0.
// NOTE (r4 post-mortem): a branchless f32-value + parallel-col variant of
// this body compiled to ~5x the VALU instructions (108us -> 428us).  Keep
// the u64 single-array guarded form -- it is the measured-best codegen
// (and op-count analysis shows u64 cmp (1 instr) + 4 cndmask/slot is already
// at parity with the best possible f32+col split).
__device__ __forceinline__ void topk_ins(uint64_t key, uint64_t (&bk)[KNN]) {
  if (key > bk[KNN - 1]) {
    #pragma unroll
    for (int j = KNN - 1; j >= 1; --j) {
      bool aj   = bk[j]     > key;
      bool ajm1 = bk[j - 1] > key;
      bk[j] = aj ? bk[j] : (ajm1 ? key : bk[j - 1]);  // uses ORIGINAL bk[j-1]
    }
    bk[0] = (bk[0] > key) ? bk[0] : key;
  }
}

// ---------------------------------------------------------------------------
// K1: y1t[b][n][o] = bn1(fc1_w @ x + fc1_b).  n-major output for gathers.
// Weights staged to LDS TRANSPOSED (wT[c][o]) so the inner loop reads 6x
// float4 at a wave-uniform LDS address (broadcast) instead of 24 first-touch
// s_load_dword per c.  (r6: fc1+fc2 staging = -25us confirmed.)
// ---------------------------------------------------------------------------
__global__ __launch_bounds__(256) void k_fc1(const float* __restrict__ x,
                                             const float* __restrict__ w,
                                             const float* __restrict__ bias,
                                             const float* __restrict__ bn,
                                             float* __restrict__ y1t) {
  __shared__ float xs[CC * 64];        // 24 KB, [c][64]
  __shared__ float wT[CC * WTS];       // 38.4 KB, wT[c*WTS + o]
  const int b = blockIdx.y, n0 = blockIdx.x * 64;
  const int t = threadIdx.x;
  for (int i = t; i < CC * 64; i += 256) {
    int c = i >> 6, nn = i & 63;
    xs[i] = x[((size_t)b * CC + c) * NN + n0 + nn];
  }
  for (int i = t; i < CC * CC; i += 256) {
    int o = i / CC, c = i % CC;        // w[o][c] row-major in global
    wT[c * WTS + o] = w[i];
  }
  __syncthreads();
  const int nn = t & 63;
  const int og = __builtin_amdgcn_readfirstlane(t >> 6);
  float acc[24];
  #pragma unroll
  for (int i = 0; i < 24; ++i) acc[i] = 0.f;
  for (int c = 0; c < CC; ++c) {
    float xv = xs[c * 64 + nn];
    const float* wp = &wT[c * WTS + og * 24];   // 16B-aligned (WTS%4==0, 24%4==0)
    float4 w0 = *(const float4*)(wp);
    float4 w1 = *(const float4*)(wp + 4);
    float4 w2 = *(const float4*)(wp + 8);
    float4 w3 = *(const float4*)(wp + 12);
    float4 w4 = *(const float4*)(wp + 16);
    float4 w5 = *(const float4*)(wp + 20);
    const float wv[24] = {w0.x, w0.y, w0.z, w0.w, w1.x, w1.y, w1.z, w1.w,
                          w2.x, w2.y, w2.z, w2.w, w3.x, w3.y, w3.z, w3.w,
                          w4.x, w4.y, w4.z, w4.w, w5.x, w5.y, w5.z, w5.w};
    #pragma unroll
    for (int oi = 0; oi < 24; ++oi) acc[oi] = fmaf(wv[oi], xv, acc[oi]);
  }
  #pragma unroll
  for (int oi = 0; oi < 24; ++oi) {
    int o = og * 24 + oi;
    float g = bn[o], be = bn[CC + o], mn = bn[2 * CC + o], vr = bn[3 * CC + o];
    float inv = g / sqrtf(vr + 1e-5f);
    float v = fmaf(acc[oi] + bias[o], inv, be - mn * inv);
    y1t[((size_t)b * NN + n0 + nn) * CC + o] = v;
  }
}

// ---------------------------------------------------------------------------
// K2: per-position L2 norm; emit bf16 split (hi, lo) of xn + sq.
// ---------------------------------------------------------------------------
__global__ __launch_bounds__(64) void k_norm(const float* __restrict__ y1t,
                                             unsigned short* __restrict__ xh,
                                             unsigned short* __restrict__ xl,
                                             float* __restrict__ sq) {
  const int p = blockIdx.x * 64 + threadIdx.x;  // 196*64 == 12544 exactly
  const float* row = y1t + (size_t)p * CC;
  float s = 0.f;
  for (int c = 0; c < CC; c += 4) {
    float4 v = *(const float4*)(row + c);
    s += v.x * v.x; s += v.y * v.y; s += v.z * v.z; s += v.w * v.w;
  }
  float inv = 1.f / fmaxf(sqrtf(s), 1e-12f);
  float sqs = 0.f;
  unsigned short* hrow = xh + (size_t)p * CC;
  unsigned short* lrow = xl + (size_t)p * CC;
  for (int c = 0; c < CC; c += 4) {
    float4 v4 = *(const float4*)(row + c);
    float v0 = v4.x * inv, v1 = v4.y * inv, v2 = v4.z * inv, v3 = v4.w * inv;
    // same accumulation order as the scalar loop -> bit-identical sq
    sqs += v0 * v0; sqs += v1 * v1; sqs += v2 * v2; sqs += v3 * v3;
    unsigned short h0 = f2bf(v0), h1 = f2bf(v1), h2 = f2bf(v2), h3 = f2bf(v3);
    float l0 = v0 - bf2f(h0), l1 = v1 - bf2f(h1), l2 = v2 - bf2f(h2), l3 = v3 - bf2f(h3);
    uint2 hv, lv;
    hv.x = (unsigned int)h0 | ((unsigned int)h1 << 16);
    hv.y = (unsigned int)h2 | ((unsigned int)h3 << 16);
    lv.x = (unsigned int)f2bf(l0) | ((unsigned int)f2bf(l1) << 16);
    lv.y = (unsigned int)f2bf(l2) | ((unsigned int)f2bf(l3) << 16);
    *(uint2*)&hrow[c] = hv;
    *(uint2*)&lrow[c] = lv;
  }
  sq[p] = sqs;
}

// ---------------------------------------------------------------------------
// K3: Gram via bf16-split MFMA with SWAPPED operands: mfma(bfrag, afrag)
// puts D-col = our Gram row, so each lane's accumulators all belong to ONE
// row (gr) and selection runs in registers.  Column chunks = gridDim.y.
// SINGLE dispatch (r6: splitting into 2 serialized half-batch dispatches
// cost +29us -- same-stream kernels don't overlap; occupancy fell 44->31%).
// Staging loop uses exact (rr,cc) decomposition -- no div/mod.
// ---------------------------------------------------------------------------
__global__ __launch_bounds__(256) void k_dist(const unsigned short* __restrict__ xh,
                                              const unsigned short* __restrict__ xl,
                                              const float* __restrict__ sq,
                                              uint64_t* __restrict__ cand_k) {
  __shared__ __align__(16) unsigned short sB[2 * 64 * 104];  // 26624 B
  __shared__ __align__(16) float sqm[TILE];
  unsigned short* BsH = sB;
  unsigned short* BsL = sB + 64 * 104;

  const int rt = blockIdx.x, chunk = blockIdx.y, b = blockIdx.z;
  const int nch = gridDim.y;
  const int r0 = rt * TILE;
  const int t = threadIdx.x;
  const int lane = t & 63, w = t >> 6;
  const int m16 = lane & 15, quad = lane >> 4;
  const int mt0 = (49 * chunk) / nch, mt1 = (49 * (chunk + 1)) / nch;

  // This lane's Gram row; A-fragments straight from global (once per block).
  const int gr = r0 + w * 16 + m16;
  bf16x8 ah[3], al[3];
  {
    const unsigned short* pH = xh + ((size_t)b * NN + gr) * CC + quad * 8;
    const unsigned short* pL = xl + ((size_t)b * NN + gr) * CC + quad * 8;
    #pragma unroll
    for (int kc = 0; kc < 3; ++kc) {
      ah[kc] = *(const bf16x8*)(pH + kc * 32);
      al[kc] = *(const bf16x8*)(pL + kc * 32);
    }
  }
  const float sr = sq[b * NN + gr];

  uint64_t bk[KNN];
  #pragma unroll
  for (int j = 0; j < KNN; ++j) bk[j] = 0ull;

  // staging decomposition: 768 items = 64 rows x 12 chunks; 256 threads x 3.
  const int rr = t >> 2, cc = t & 3;

  for (int mt = mt0; mt < mt1; ++mt) {
    const int m0 = mt * TILE;
    __syncthreads();  // prior tile's B-frag reads done before overwrite
    {
      const uint4* rowH = (const uint4*)(xh + ((size_t)b * NN + m0 + rr) * CC);
      const uint4* rowL = (const uint4*)(xl + ((size_t)b * NN + m0 + rr) * CC);
      #pragma unroll
      for (int k = 0; k < 3; ++k) {
        int ch = cc + 4 * k;
        *(uint4*)&BsH[rr * 104 + ch * 8] = rowH[ch];
        *(uint4*)&BsL[rr * 104 + ch * 8] = rowL[ch];
      }
    }
    if (t < TILE) sqm[t] = sq[b * NN + m0 + t];
    __syncthreads();

    #pragma unroll
    for (int tt = 0; tt < 4; ++tt) {
      const int brow = (tt * 16 + m16) * 104 + quad * 8;
      f32x4 acc = {0.f, 0.f, 0.f, 0.f};
      #pragma unroll
      for (int kc = 0; kc < 3; ++kc) {
        bf16x8 bh = *(const bf16x8*)&BsH[brow + kc * 32];
        bf16x8 bl = *(const bf16x8*)&BsL[brow + kc * 32];
        acc = __builtin_amdgcn_mfma_f32_16x16x32_bf16(bh, ah[kc], acc, 0, 0, 0);
        acc = __builtin_amdgcn_mfma_f32_16x16x32_bf16(bl, ah[kc], acc, 0, 0, 0);
        acc = __builtin_amdgcn_mfma_f32_16x16x32_bf16(bh, al[kc], acc, 0, 0, 0);
      }
      // lane's candidates: cols m0 + tt*16 + quad*4 + r, all for row gr
      float4 s4 = *(const float4*)&sqm[tt * 16 + quad * 4];  // broadcast read
      const float sv[4] = {s4.x, s4.y, s4.z, s4.w};
      #pragma unroll
      for (int r = 0; r < 4; ++r) {
        float v = 2.f * acc[r] - sr - sv[r];
        int col = m0 + tt * 16 + quad * 4 + r;
        uint64_t key = ((uint64_t)fmono(v) << 32) | (unsigned int)~col;
        topk_ins(key, bk);
      }
    }
  }
  __syncthreads();

  // merge the 4 per-quad lists of each row (scratch aliases sB)
  uint64_t* sk = (uint64_t*)sB;   // 64 rows * 4 quads * 9 * 8B = 18432 B
  #pragma unroll
  for (int j = 0; j < KNN; ++j) sk[((w * 16 + m16) * 4 + quad) * KNN + j] = bk[j];
  __syncthreads();
  if (t < TILE) {
    uint64_t fk[KNN];
    #pragma unroll
    for (int j = 0; j < KNN; ++j) fk[j] = 0ull;
    for (int qq = 0; qq < 4; ++qq)
      #pragma unroll
      for (int j = 0; j < KNN; ++j)
        topk_ins(sk[(t * 4 + qq) * KNN + j], fk);
    size_t base = (((size_t)b * nch + chunk) * NN + r0 + t) * KNN;
    #pragma unroll
    for (int j = 0; j < KNN; ++j) cand_k[base + j] = fk[j];
  }
}

// ---------------------------------------------------------------------------
// K4: merge nch chunk lists -> nn_idx (clamped to valid range).
// ---------------------------------------------------------------------------
__global__ __launch_bounds__(64) void k_nnmerge(const uint64_t* __restrict__ cand_k,
                                                int* __restrict__ nn_idx, int nch) {
  const int p = blockIdx.x * 64 + threadIdx.x;
  const int b = p / NN, n = p % NN;
  uint64_t fk[KNN];
  #pragma unroll
  for (int j = 0; j < KNN; ++j) fk[j] = 0ull;
  for (int ch = 0; ch < nch; ++ch) {
    size_t base = (((size_t)b * nch + ch) * NN + n) * KNN;
    #pragma unroll
    for (int j = 0; j < KNN; ++j) topk_ins(cand_k[base + j], fk);
  }
  #pragma unroll
  for (int j = 0; j < KNN; ++j) {
    int v = (int)(~(unsigned int)fk[j]);
    if ((unsigned)v >= (unsigned)NN) v = 0;  // sentinel guard: no wild gathers
    nn_idx[(size_t)p * KNN + j] = v;
  }
}

// ---------------------------------------------------------------------------
// K5: gather + grouped conv + bias + bn + relu + max over K.
// k-dep half remapped: half = l>>4 picks the db block, so each lane's f-rows
// are LDS-broadcast float4 reads (3 per c) instead of 9+ lane-variant reads.
// fj row span = FJR(580) floats: p/half groups land on distinct bank quads.
// ---------------------------------------------------------------------------
__global__ __launch_bounds__(256) void k_gconv(const float* __restrict__ y1t,
                                               const int* __restrict__ nn_idx,
                                               const float* __restrict__ gw,
                                               const float* __restrict__ gb,
                                               const float* __restrict__ bng,
                                               float* __restrict__ ymax) {
  __shared__ float wl[C2 * 49];
  __shared__ float xi[PT * CC];
  __shared__ __align__(16) float fj[PT * 2 * FJR];
  __shared__ int idxl[PT * KNN];
  const int t = threadIdx.x;
  const int p0 = blockIdx.x * PT;
  const int b0 = p0 / NN;

  for (int i = t; i < C2 * 48; i += 256) wl[(i / 48) * 49 + (i % 48)] = gw[i];
  if (t < PT * KNN) {
    int v = nn_idx[(size_t)p0 * KNN + t];
    idxl[t] = ((unsigned)v < (unsigned)NN) ? v : 0;
  }
  for (int i = t; i < PT * CC; i += 256) xi[i] = y1t[(size_t)p0 * CC + i];
  __syncthreads();

  for (int i = t; i < PT * KNN * CC; i += 256) {
    int pk = i / CC, c = i % CC;
    int p = pk / KNN, k = pk % KNN;
    int j = idxl[p * KNN + k];
    float v = y1t[((size_t)b0 * NN + j) * CC + c] - xi[p * CC + c];
    int h = (c >= 48) ? 1 : 0;
    fj[((p * 2 + h) * FJR) + (c - h * 48) * 12 + k] = v;
  }
  __syncthreads();

  const int p = t >> 5, l = t & 31;
  const size_t pg = p0 + p;
  float* orow = ymax + pg * C2;
  const float* xip = xi + p * CC;

  auto bnrelu = [&](int oc, float a) -> float {
    float g = bng[oc], be = bng[C2 + oc], mn = bng[2 * C2 + oc], vr = bng[3 * C2 + oc];
    float inv = g / sqrtf(vr + 1e-5f);
    return fmaxf(fmaf(a + gb[oc], inv, be - mn * inv), 0.f);
  };

  {  // k-free half
    const int oc0 = l, oc1 = l + 32, oc2 = l + 64;
    const int cb0 = (oc0 / 48) * 48, cb1 = (oc1 / 48) * 48, cb2 = (oc2 / 48) * 48;
    float a0 = 0.f, a1 = 0.f, a2 = 0.f;
    #pragma unroll 8
    for (int c = 0; c < 48; ++c) {
      a0 = fmaf(wl[oc0 * 49 + c], xip[cb0 + c], a0);
      a1 = fmaf(wl[oc1 * 49 + c], xip[cb1 + c], a1);
      a2 = fmaf(wl[oc2 * 49 + c], xip[cb2 + c], a2);
    }
    orow[oc0] = bnrelu(oc0, a0);
    orow[oc1] = bnrelu(oc1, a1);
    orow[oc2] = bnrelu(oc2, a2);
  }
  {  // k-dependent half (lane-remapped: uniform db per lane)
    const int half = l >> 4, lsub = l & 15;
    const int oc0 = 96 + half * 48 + lsub, oc1 = oc0 + 16, oc2 = oc0 + 32;
    const float* fbase = fj + ((size_t)p * 2 + half) * FJR;
    float acc0[KNN], acc1[KNN], acc2[KNN];
    #pragma unroll
    for (int k = 0; k < KNN; ++k) { acc0[k] = 0.f; acc1[k] = 0.f; acc2[k] = 0.f; }
    #pragma unroll 2
    for (int c = 0; c < 48; ++c) {
      float w0 = wl[oc0 * 49 + c], w1 = wl[oc1 * 49 + c], w2 = wl[oc2 * 49 + c];
      const float* fr = fbase + c * 12;
      float4 fA = *(const float4*)(fr);      // k 0..3 (16B-aligned: FJR*4%16==0)
      float4 fB = *(const float4*)(fr + 4);  // k 4..7
      float f8 = fr[8];
      const float fk[KNN] = {fA.x, fA.y, fA.z, fA.w, fB.x, fB.y, fB.z, fB.w, f8};
      #pragma unroll
      for (int k = 0; k < KNN; ++k) {
        acc0[k] = fmaf(w0, fk[k], acc0[k]);
        acc1[k] = fmaf(w1, fk[k], acc1[k]);
        acc2[k] = fmaf(w2, fk[k], acc2[k]);
      }
    }
    {
      float g = bng[oc0], be = bng[C2 + oc0], mn = bng[2 * C2 + oc0], vr = bng[3 * C2 + oc0];
      float inv = g / sqrtf(vr + 1e-5f), sh = be - mn * inv, bs = gb[oc0], m = 0.f;
      #pragma unroll
      for (int k = 0; k < KNN; ++k) m = fmaxf(m, fmaxf(fmaf(acc0[k] + bs, inv, sh), 0.f));
      orow[oc0] = m;
    }
    {
      float g = bng[oc1], be = bng[C2 + oc1], mn = bng[2 * C2 + oc1], vr = bng[3 * C2 + oc1];
      float inv = g / sqrtf(vr + 1e-5f), sh = be - mn * inv, bs = gb[oc1], m = 0.f;
      #pragma unroll
      for (int k = 0; k < KNN; ++k) m = fmaxf(m, fmaxf(fmaf(acc1[k] + bs, inv, sh), 0.f));
      orow[oc1] = m;
    }
    {
      float g = bng[oc2], be = bng[C2 + oc2], mn = bng[2 * C2 + oc2], vr = bng[3 * C2 + oc2];
      float inv = g / sqrtf(vr + 1e-5f), sh = be - mn * inv, bs = gb[oc2], m = 0.f;
      #pragma unroll
      for (int k = 0; k < KNN; ++k) m = fmaxf(m, fmaxf(fmaf(acc2[k] + bs, inv, sh), 0.f));
      orow[oc2] = m;
    }
  }
}

// ---------------------------------------------------------------------------
// K6: out = bn2(fc2_w @ ymax + fc2_b) + x
// w2 staged to LDS transposed (same rationale as K1).  LDS = 126 KB.
// ---------------------------------------------------------------------------
__global__ __launch_bounds__(256) void k_fc2(const float* __restrict__ ymax,
                                             const float* __restrict__ w2,
                                             const float* __restrict__ b2,
                                             const float* __restrict__ bn2,
                                             const float* __restrict__ xin,
                                             float* __restrict__ out) {
  __shared__ float ys[64 * 193];       // 49.4 KB
  __shared__ float w2T[C2 * WTS];      // 76.8 KB, w2T[c2*WTS + o]
  const int b = blockIdx.y, n0 = blockIdx.x * 64, t = threadIdx.x;
  for (int i = t; i < 64 * C2; i += 256) {
    int nn = i / C2, c2 = i % C2;
    ys[nn * 193 + c2] = ymax[((size_t)b * NN + n0 + nn) * C2 + c2];
  }
  for (int i = t; i < CC * C2; i += 256) {
    int o = i / C2, c2 = i % C2;       // w2[o][c2] row-major in global
    w2T[c2 * WTS + o] = w2[i];
  }
  __syncthreads();
  const int nn = t & 63;
  const int og = __builtin_amdgcn_readfirstlane(t >> 6);
  float acc[24];
  #pragma unroll
  for (int i = 0; i < 24; ++i) acc[i] = 0.f;
  const float* yrow = ys + nn * 193;
  for (int c2 = 0; c2 < C2; ++c2) {
    float yv = yrow[c2];
    const float* wp = &w2T[c2 * WTS + og * 24];  // 16B-aligned
    float4 w0 = *(const float4*)(wp);
    float4 w1 = *(const float4*)(wp + 4);
    float4 w2v = *(const float4*)(wp + 8);
    float4 w3 = *(const float4*)(wp + 12);
    float4 w4 = *(const float4*)(wp + 16);
    float4 w5 = *(const float4*)(wp + 20);
    const float wv[24] = {w0.x, w0.y, w0.z, w0.w, w1.x, w1.y, w1.z, w1.w,
                          w2v.x, w2v.y, w2v.z, w2v.w, w3.x, w3.y, w3.z, w3.w,
                          w4.x, w4.y, w4.z, w4.w, w5.x, w5.y, w5.z, w5.w};
    #pragma unroll
    for (int oi = 0; oi < 24; ++oi) acc[oi] = fmaf(wv[oi], yv, acc[oi]);
  }
  #pragma unroll
  for (int oi = 0; oi < 24; ++oi) {
    int o = og * 24 + oi;
    float g = bn2[o], be = bn2[CC + o], mn = bn2[2 * CC + o], vr = bn2[3 * CC + o];
    float inv = g / sqrtf(vr + 1e-5f);
    float v = fmaf(acc[oi] + b2[o], inv, be - mn * inv);
    size_t off = ((size_t)b * CC + o) * NN + n0 + nn;
    out[off] = v + xin[off];
  }
}

// ---------------------------------------------------------------------------
extern "C" void kernel_launch(void* const* d_in, const int* in_sizes, int n_in,
                              void* d_out, int out_size, void* d_ws, size_t ws_size,
                              hipStream_t stream) {
  const float* x     = (const float*)d_in[0];
  const float* fc1_w = (const float*)d_in[1];
  const float* fc1_b = (const float*)d_in[2];
  const float* bn1   = (const float*)d_in[3];
  const float* gc_w  = (const float*)d_in[4];
  const float* gc_b  = (const float*)d_in[5];
  const float* bng   = (const float*)d_in[6];
  const float* fc2_w = (const float*)d_in[7];
  const float* fc2_b = (const float*)d_in[8];
  const float* bn2   = (const float*)d_in[9];
  float* out = (float*)d_out;

  const size_t BNC = (size_t)BN_ * NN * CC;
  float* ws = (float*)d_ws;
  float* y1t = ws;                                   // B*N*C fp32
  unsigned short* xh = (unsigned short*)(y1t + BNC); // B*N*C bf16 hi
  unsigned short* xl = xh + BNC;                     // B*N*C bf16 lo
  float* sq     = ws + 2 * BNC;                      // B*N
  float* ymax   = sq + (size_t)BN_ * NN;             // B*N*C2 fp32
  int* nnidx = (int*)(ymax + (size_t)BN_ * NN * C2);

  // NCH=16 needs a dedicated cand_k region (14.45 MB) after nnidx; total
  // footprint 34.3 MB.  If ws is smaller, fall back to the verified NCH=8
  // layout with cand_k aliased onto ymax (7.2 MB <= 9.6 MB; cand_k is fully
  // consumed by k_nnmerge before k_gconv writes ymax -- single stream).
  const size_t base_bytes =
      (2 * BNC + (size_t)BN_ * NN + (size_t)BN_ * NN * C2) * 4 +
      (size_t)BN_ * NN * KNN * 4;                    // through nnidx
  const size_t need16 = base_bytes + (size_t)BN_ * 16 * NN * KNN * 8;
  int nch;
  uint64_t* cand_k;
  if (ws_size >= need16) {
    nch = 16;
    cand_k = (uint64_t*)((char*)d_ws + base_bytes);  // 8B-aligned (base%8==0)
  } else {
    nch = 8;
    cand_k = (uint64_t*)ymax;
  }

  k_fc1<<<dim3(NN / 64, BN_), 256, 0, stream>>>(x, fc1_w, fc1_b, bn1, y1t);
  k_norm<<<dim3((BN_ * NN) / 64), 64, 0, stream>>>(y1t, xh, xl, sq);
  k_dist<<<dim3(NN / TILE, nch, BN_), 256, 0, stream>>>(xh, xl, sq, cand_k);
  k_nnmerge<<<dim3((BN_ * NN) / 64), 64, 0, stream>>>(cand_k, nnidx, nch);
  k_gconv<<<dim3((BN_ * NN) / PT), 256, 0, stream>>>(y1t, nnidx, gc_w, gc_b, bng, ymax);
  k_fc2<<<dim3(NN / 64, BN_), 256, 0, stream>>>(ymax, fc2_w, fc2_b, bn2, x, out);
}

// Round 9
// 287.837 us; speedup vs baseline: 1.1306x; 1.0401x over previous
//
#include <hip/hip_runtime.h>
#include <cstdint>
#include <cstddef>
#include <math.h>

#define BN_   4
#define CC    96
#define C2    192
#define NN    3136
#define KNN   9
#define TILE  64
#define PT    8
#define FJR   580   /* 48*12 + 4 skew: keeps p/half broadcast groups on distinct bank quads */
#define WTS   100   /* transposed-weight LDS row stride: %4==0 (16B-aligned float4 rows) */

typedef __attribute__((ext_vector_type(8))) __bf16 bf16x8;
typedef __attribute__((ext_vector_type(4))) float f32x4;

__device__ __forceinline__ unsigned short f2bf(float f) {
  unsigned int u = __float_as_uint(f);
  unsigned int r = u + 0x7fffu + ((u >> 16) & 1u);   // RNE
  return (unsigned short)(r >> 16);
}
__device__ __forceinline__ float bf2f(unsigned short h) {
  return __uint_as_float(((unsigned int)h) << 16);
}
// monotone map: fmono(a) > fmono(b)  <=>  a > b  (as floats)
__device__ __forceinline__ unsigned int fmono(float f) {
  unsigned int s = __float_as_uint(f);
  return s ^ ((unsigned int)((int)s >> 31) | 0x80000000u);
}

// top-9 of u64 keys kept as a SORTED-DESCENDING list; insert-by-shift.
// key = (fmono(v)<<32) | ~idx  => value desc, idx asc (jax top_k tie-break).
// Keys are unique (col in low bits); real keys are always > 0; init = all 0.
// NOTE (r4 post-mortem): a branchless f32-value + parallel-col variant of
// this body compiled to ~5x the VALU instructions (108us -> 428us).  Keep
// the u64 single-array guarded form -- it is the measured-best codegen.
__device__ __forceinline__ void topk_ins(uint64_t key, uint64_t (&bk)[KNN]) {
  if (key > bk[KNN - 1]) {
    #pragma unroll
    for (int j = KNN - 1; j >= 1; --j) {
      bool aj   = bk[j]     > key;
      bool ajm1 = bk[j - 1] > key;
      bk[j] = aj ? bk[j] : (ajm1 ? key : bk[j - 1]);  // uses ORIGINAL bk[j-1]
    }
    bk[0] = (bk[0] > key) ? bk[0] : key;
  }
}

// ---------------------------------------------------------------------------
// K1: y1t[b][n][o] = bn1(fc1_w @ x + fc1_b), n-major -- FUSED with the
// per-position L2-norm/bf16-split (old k_norm): each block computes complete
// rows n0..n0+63, so the row lives in LDS (ys) and wave 0 runs the verbatim
// k_norm body from LDS after a barrier.  Same float4-group accumulation
// order -> bit-identical sq/xh/xl; kills one launch + a 4.8MB y1t re-read.
// LDS: 24 + 38.4 + 24.6 = 87.5 KB (196 blocks <= 256 CUs, occupancy moot).
// ---------------------------------------------------------------------------
__global__ __launch_bounds__(256) void k_fc1(const float* __restrict__ x,
                                             const float* __restrict__ w,
                                             const float* __restrict__ bias,
                                             const float* __restrict__ bn,
                                             float* __restrict__ y1t,
                                             unsigned short* __restrict__ xh,
                                             unsigned short* __restrict__ xl,
                                             float* __restrict__ sq) {
  __shared__ float xs[CC * 64];                 // 24 KB, [c][64]
  __shared__ float wT[CC * WTS];                // 38.4 KB, wT[c*WTS + o]
  __shared__ __align__(16) float ys[64 * CC];   // 24.6 KB, [nn][c]
  const int b = blockIdx.y, n0 = blockIdx.x * 64;
  const int t = threadIdx.x;
  for (int i = t; i < CC * 64; i += 256) {
    int c = i >> 6, nn = i & 63;
    xs[i] = x[((size_t)b * CC + c) * NN + n0 + nn];
  }
  for (int i = t; i < CC * CC; i += 256) {
    int o = i / CC, c = i % CC;        // w[o][c] row-major in global
    wT[c * WTS + o] = w[i];
  }
  __syncthreads();
  const int nn = t & 63;
  const int og = __builtin_amdgcn_readfirstlane(t >> 6);
  float acc[24];
  #pragma unroll
  for (int i = 0; i < 24; ++i) acc[i] = 0.f;
  for (int c = 0; c < CC; ++c) {
    float xv = xs[c * 64 + nn];
    const float* wp = &wT[c * WTS + og * 24];   // 16B-aligned (WTS%4==0, 24%4==0)
    float4 w0 = *(const float4*)(wp);
    float4 w1 = *(const float4*)(wp + 4);
    float4 w2 = *(const float4*)(wp + 8);
    float4 w3 = *(const float4*)(wp + 12);
    float4 w4 = *(const float4*)(wp + 16);
    float4 w5 = *(const float4*)(wp + 20);
    const float wv[24] = {w0.x, w0.y, w0.z, w0.w, w1.x, w1.y, w1.z, w1.w,
                          w2.x, w2.y, w2.z, w2.w, w3.x, w3.y, w3.z, w3.w,
                          w4.x, w4.y, w4.z, w4.w, w5.x, w5.y, w5.z, w5.w};
    #pragma unroll
    for (int oi = 0; oi < 24; ++oi) acc[oi] = fmaf(wv[oi], xv, acc[oi]);
  }
  #pragma unroll
  for (int oi = 0; oi < 24; ++oi) {
    int o = og * 24 + oi;
    float g = bn[o], be = bn[CC + o], mn = bn[2 * CC + o], vr = bn[3 * CC + o];
    float inv = g / sqrtf(vr + 1e-5f);
    float v = fmaf(acc[oi] + bias[o], inv, be - mn * inv);
    y1t[((size_t)b * NN + n0 + nn) * CC + o] = v;
    ys[nn * CC + o] = v;
  }
  __syncthreads();

  // --- fused norm (verbatim old k_norm body, reading the LDS row) ---
  if (t < 64) {
    const size_t p = (size_t)b * NN + n0 + t;
    const float* row = &ys[t * CC];             // 16B-aligned (t*384)
    float s = 0.f;
    for (int c = 0; c < CC; c += 4) {
      float4 v = *(const float4*)(row + c);
      s += v.x * v.x; s += v.y * v.y; s += v.z * v.z; s += v.w * v.w;
    }
    float inv = 1.f / fmaxf(sqrtf(s), 1e-12f);
    float sqs = 0.f;
    unsigned short* hrow = xh + p * CC;
    unsigned short* lrow = xl + p * CC;
    for (int c = 0; c < CC; c += 4) {
      float4 v4 = *(const float4*)(row + c);
      float v0 = v4.x * inv, v1 = v4.y * inv, v2 = v4.z * inv, v3 = v4.w * inv;
      sqs += v0 * v0; sqs += v1 * v1; sqs += v2 * v2; sqs += v3 * v3;
      unsigned short h0 = f2bf(v0), h1 = f2bf(v1), h2 = f2bf(v2), h3 = f2bf(v3);
      float l0 = v0 - bf2f(h0), l1 = v1 - bf2f(h1), l2 = v2 - bf2f(h2), l3 = v3 - bf2f(h3);
      uint2 hv, lv;
      hv.x = (unsigned int)h0 | ((unsigned int)h1 << 16);
      hv.y = (unsigned int)h2 | ((unsigned int)h3 << 16);
      lv.x = (unsigned int)f2bf(l0) | ((unsigned int)f2bf(l1) << 16);
      lv.y = (unsigned int)f2bf(l2) | ((unsigned int)f2bf(l3) << 16);
      *(uint2*)&hrow[c] = hv;
      *(uint2*)&lrow[c] = lv;
    }
    sq[p] = sqs;
  }
}

// ---------------------------------------------------------------------------
// K3: Gram via bf16-split MFMA with SWAPPED operands: mfma(bfrag, afrag)
// puts D-col = our Gram row, so each lane's accumulators all belong to ONE
// row (gr) and selection runs in registers.  Column chunks = gridDim.y.
// r5-EXACT body (measured 107us; r7's (rr,cc) staging tweak cost VGPR 40->44
// and +4us -- reverted; this kernel's codegen is fragile, do not touch).
// ---------------------------------------------------------------------------
__global__ __launch_bounds__(256) void k_dist(const unsigned short* __restrict__ xh,
                                              const unsigned short* __restrict__ xl,
                                              const float* __restrict__ sq,
                                              uint64_t* __restrict__ cand_k) {
  __shared__ __align__(16) unsigned short sB[2 * 64 * 104];  // 26624 B
  __shared__ __align__(16) float sqm[TILE];
  unsigned short* BsH = sB;
  unsigned short* BsL = sB + 64 * 104;

  const int rt = blockIdx.x, chunk = blockIdx.y, b = blockIdx.z;
  const int nch = gridDim.y;
  const int r0 = rt * TILE;
  const int t = threadIdx.x;
  const int lane = t & 63, w = t >> 6;
  const int m16 = lane & 15, quad = lane >> 4;
  const int mt0 = (49 * chunk) / nch, mt1 = (49 * (chunk + 1)) / nch;

  // This lane's Gram row; A-fragments straight from global (once per block).
  const int gr = r0 + w * 16 + m16;
  bf16x8 ah[3], al[3];
  {
    const unsigned short* pH = xh + ((size_t)b * NN + gr) * CC + quad * 8;
    const unsigned short* pL = xl + ((size_t)b * NN + gr) * CC + quad * 8;
    #pragma unroll
    for (int kc = 0; kc < 3; ++kc) {
      ah[kc] = *(const bf16x8*)(pH + kc * 32);
      al[kc] = *(const bf16x8*)(pL + kc * 32);
    }
  }
  const float sr = sq[b * NN + gr];

  uint64_t bk[KNN];
  #pragma unroll
  for (int j = 0; j < KNN; ++j) bk[j] = 0ull;

  for (int mt = mt0; mt < mt1; ++mt) {
    const int m0 = mt * TILE;
    __syncthreads();  // prior tile's B-frag reads done before overwrite
    for (int i = t; i < 64 * 12; i += 256) {
      int r = i / 12, ch = i % 12;
      const uint4* sH = (const uint4*)(xh + ((size_t)b * NN + m0 + r) * CC);
      const uint4* sL = (const uint4*)(xl + ((size_t)b * NN + m0 + r) * CC);
      *(uint4*)&BsH[r * 104 + ch * 8] = sH[ch];
      *(uint4*)&BsL[r * 104 + ch * 8] = sL[ch];
    }
    if (t < TILE) sqm[t] = sq[b * NN + m0 + t];
    __syncthreads();

    #pragma unroll
    for (int tt = 0; tt < 4; ++tt) {
      const int brow = (tt * 16 + m16) * 104 + quad * 8;
      f32x4 acc = {0.f, 0.f, 0.f, 0.f};
      #pragma unroll
      for (int kc = 0; kc < 3; ++kc) {
        bf16x8 bh = *(const bf16x8*)&BsH[brow + kc * 32];
        bf16x8 bl = *(const bf16x8*)&BsL[brow + kc * 32];
        acc = __builtin_amdgcn_mfma_f32_16x16x32_bf16(bh, ah[kc], acc, 0, 0, 0);
        acc = __builtin_amdgcn_mfma_f32_16x16x32_bf16(bl, ah[kc], acc, 0, 0, 0);
        acc = __builtin_amdgcn_mfma_f32_16x16x32_bf16(bh, al[kc], acc, 0, 0, 0);
      }
      // lane's candidates: cols m0 + tt*16 + quad*4 + r, all for row gr
      float4 s4 = *(const float4*)&sqm[tt * 16 + quad * 4];  // broadcast read
      const float sv[4] = {s4.x, s4.y, s4.z, s4.w};
      #pragma unroll
      for (int r = 0; r < 4; ++r) {
        float v = 2.f * acc[r] - sr - sv[r];
        int col = m0 + tt * 16 + quad * 4 + r;
        uint64_t key = ((uint64_t)fmono(v) << 32) | (unsigned int)~col;
        topk_ins(key, bk);
      }
    }
  }
  __syncthreads();

  // merge the 4 per-quad lists of each row (scratch aliases sB)
  uint64_t* sk = (uint64_t*)sB;   // 64 rows * 4 quads * 9 * 8B = 18432 B
  #pragma unroll
  for (int j = 0; j < KNN; ++j) sk[((w * 16 + m16) * 4 + quad) * KNN + j] = bk[j];
  __syncthreads();
  if (t < TILE) {
    uint64_t fk[KNN];
    #pragma unroll
    for (int j = 0; j < KNN; ++j) fk[j] = 0ull;
    for (int qq = 0; qq < 4; ++qq)
      #pragma unroll
      for (int j = 0; j < KNN; ++j)
        topk_ins(sk[(t * 4 + qq) * KNN + j], fk);
    size_t base = (((size_t)b * nch + chunk) * NN + r0 + t) * KNN;
    #pragma unroll
    for (int j = 0; j < KNN; ++j) cand_k[base + j] = fk[j];
  }
}

// ---------------------------------------------------------------------------
// K4: merge nch chunk lists -> nn_idx.  PARALLELIZED (r7: old 196x64 launch
// was 0.19 waves/SIMD with a 144-insert serial chain): 256-thread blocks,
// 4 sub-waves each merge nch/4 chunks (36 inserts), then sub-wave 0 merges
// the 4 partial lists via LDS.  u64 keys make the merge tree exactly
// equivalent to the sequential merge (ties resolved inside the key).
// ---------------------------------------------------------------------------
__global__ __launch_bounds__(256) void k_nnmerge(const uint64_t* __restrict__ cand_k,
                                                 int* __restrict__ nn_idx, int nch) {
  __shared__ uint64_t sk[64 * 4 * KNN];   // 18432 B
  const int t = threadIdx.x, lane = t & 63, sw = t >> 6;
  const int p = blockIdx.x * 64 + lane;
  const int b = p / NN, n = p % NN;
  const int cpw = nch >> 2;               // chunks per sub-wave (nch = 8 or 16)
  uint64_t fk[KNN];
  #pragma unroll
  for (int j = 0; j < KNN; ++j) fk[j] = 0ull;
  for (int ch = sw * cpw; ch < (sw + 1) * cpw; ++ch) {
    size_t base = (((size_t)b * nch + ch) * NN + n) * KNN;
    #pragma unroll
    for (int j = 0; j < KNN; ++j) topk_ins(cand_k[base + j], fk);
  }
  #pragma unroll
  for (int j = 0; j < KNN; ++j) sk[(lane * 4 + sw) * KNN + j] = fk[j];
  __syncthreads();
  if (sw == 0) {
    uint64_t gk[KNN];
    #pragma unroll
    for (int j = 0; j < KNN; ++j) gk[j] = 0ull;
    for (int q = 0; q < 4; ++q)
      #pragma unroll
      for (int j = 0; j < KNN; ++j)
        topk_ins(sk[(lane * 4 + q) * KNN + j], gk);
    #pragma unroll
    for (int j = 0; j < KNN; ++j) {
      int v = (int)(~(unsigned int)gk[j]);
      if ((unsigned)v >= (unsigned)NN) v = 0;  // sentinel guard
      nn_idx[(size_t)p * KNN + j] = v;
    }
  }
}

// ---------------------------------------------------------------------------
// K5: gather + grouped conv + bias + bn + relu + max over K.
// k-dep half remapped: half = l>>4 picks the db block, so each lane's f-rows
// are LDS-broadcast float4 reads (3 per c) instead of 9+ lane-variant reads.
// fj row span = FJR(580) floats: p/half groups land on distinct bank quads.
// ---------------------------------------------------------------------------
__global__ __launch_bounds__(256) void k_gconv(const float* __restrict__ y1t,
                                               const int* __restrict__ nn_idx,
                                               const float* __restrict__ gw,
                                               const float* __restrict__ gb,
                                               const float* __restrict__ bng,
                                               float* __restrict__ ymax) {
  __shared__ float wl[C2 * 49];
  __shared__ float xi[PT * CC];
  __shared__ __align__(16) float fj[PT * 2 * FJR];
  __shared__ int idxl[PT * KNN];
  const int t = threadIdx.x;
  const int p0 = blockIdx.x * PT;
  const int b0 = p0 / NN;

  for (int i = t; i < C2 * 48; i += 256) wl[(i / 48) * 49 + (i % 48)] = gw[i];
  if (t < PT * KNN) {
    int v = nn_idx[(size_t)p0 * KNN + t];
    idxl[t] = ((unsigned)v < (unsigned)NN) ? v : 0;
  }
  for (int i = t; i < PT * CC; i += 256) xi[i] = y1t[(size_t)p0 * CC + i];
  __syncthreads();

  for (int i = t; i < PT * KNN * CC; i += 256) {
    int pk = i / CC, c = i % CC;
    int p = pk / KNN, k = pk % KNN;
    int j = idxl[p * KNN + k];
    float v = y1t[((size_t)b0 * NN + j) * CC + c] - xi[p * CC + c];
    int h = (c >= 48) ? 1 : 0;
    fj[((p * 2 + h) * FJR) + (c - h * 48) * 12 + k] = v;
  }
  __syncthreads();

  const int p = t >> 5, l = t & 31;
  const size_t pg = p0 + p;
  float* orow = ymax + pg * C2;
  const float* xip = xi + p * CC;

  auto bnrelu = [&](int oc, float a) -> float {
    float g = bng[oc], be = bng[C2 + oc], mn = bng[2 * C2 + oc], vr = bng[3 * C2 + oc];
    float inv = g / sqrtf(vr + 1e-5f);
    return fmaxf(fmaf(a + gb[oc], inv, be - mn * inv), 0.f);
  };

  {  // k-free half
    const int oc0 = l, oc1 = l + 32, oc2 = l + 64;
    const int cb0 = (oc0 / 48) * 48, cb1 = (oc1 / 48) * 48, cb2 = (oc2 / 48) * 48;
    float a0 = 0.f, a1 = 0.f, a2 = 0.f;
    #pragma unroll 8
    for (int c = 0; c < 48; ++c) {
      a0 = fmaf(wl[oc0 * 49 + c], xip[cb0 + c], a0);
      a1 = fmaf(wl[oc1 * 49 + c], xip[cb1 + c], a1);
      a2 = fmaf(wl[oc2 * 49 + c], xip[cb2 + c], a2);
    }
    orow[oc0] = bnrelu(oc0, a0);
    orow[oc1] = bnrelu(oc1, a1);
    orow[oc2] = bnrelu(oc2, a2);
  }
  {  // k-dependent half (lane-remapped: uniform db per lane)
    const int half = l >> 4, lsub = l & 15;
    const int oc0 = 96 + half * 48 + lsub, oc1 = oc0 + 16, oc2 = oc0 + 32;
    const float* fbase = fj + ((size_t)p * 2 + half) * FJR;
    float acc0[KNN], acc1[KNN], acc2[KNN];
    #pragma unroll
    for (int k = 0; k < KNN; ++k) { acc0[k] = 0.f; acc1[k] = 0.f; acc2[k] = 0.f; }
    #pragma unroll 2
    for (int c = 0; c < 48; ++c) {
      float w0 = wl[oc0 * 49 + c], w1 = wl[oc1 * 49 + c], w2 = wl[oc2 * 49 + c];
      const float* fr = fbase + c * 12;
      float4 fA = *(const float4*)(fr);      // k 0..3 (16B-aligned: FJR*4%16==0)
      float4 fB = *(const float4*)(fr + 4);  // k 4..7
      float f8 = fr[8];
      const float fk[KNN] = {fA.x, fA.y, fA.z, fA.w, fB.x, fB.y, fB.z, fB.w, f8};
      #pragma unroll
      for (int k = 0; k < KNN; ++k) {
        acc0[k] = fmaf(w0, fk[k], acc0[k]);
        acc1[k] = fmaf(w1, fk[k], acc1[k]);
        acc2[k] = fmaf(w2, fk[k], acc2[k]);
      }
    }
    {
      float g = bng[oc0], be = bng[C2 + oc0], mn = bng[2 * C2 + oc0], vr = bng[3 * C2 + oc0];
      float inv = g / sqrtf(vr + 1e-5f), sh = be - mn * inv, bs = gb[oc0], m = 0.f;
      #pragma unroll
      for (int k = 0; k < KNN; ++k) m = fmaxf(m, fmaxf(fmaf(acc0[k] + bs, inv, sh), 0.f));
      orow[oc0] = m;
    }
    {
      float g = bng[oc1], be = bng[C2 + oc1], mn = bng[2 * C2 + oc1], vr = bng[3 * C2 + oc1];
      float inv = g / sqrtf(vr + 1e-5f), sh = be - mn * inv, bs = gb[oc1], m = 0.f;
      #pragma unroll
      for (int k = 0; k < KNN; ++k) m = fmaxf(m, fmaxf(fmaf(acc1[k] + bs, inv, sh), 0.f));
      orow[oc1] = m;
    }
    {
      float g = bng[oc2], be = bng[C2 + oc2], mn = bng[2 * C2 + oc2], vr = bng[3 * C2 + oc2];
      float inv = g / sqrtf(vr + 1e-5f), sh = be - mn * inv, bs = gb[oc2], m = 0.f;
      #pragma unroll
      for (int k = 0; k < KNN; ++k) m = fmaxf(m, fmaxf(fmaf(acc2[k] + bs, inv, sh), 0.f));
      orow[oc2] = m;
    }
  }
}

// ---------------------------------------------------------------------------
// K6: out = bn2(fc2_w @ ymax + fc2_b) + x
// w2 staged to LDS transposed (same rationale as K1).  LDS = 126 KB.
// ---------------------------------------------------------------------------
__global__ __launch_bounds__(256) void k_fc2(const float* __restrict__ ymax,
                                             const float* __restrict__ w2,
                                             const float* __restrict__ b2,
                                             const float* __restrict__ bn2,
                                             const float* __restrict__ xin,
                                             float* __restrict__ out) {
  __shared__ float ys[64 * 193];       // 49.4 KB
  __shared__ float w2T[C2 * WTS];      // 76.8 KB, w2T[c2*WTS + o]
  const int b = blockIdx.y, n0 = blockIdx.x * 64, t = threadIdx.x;
  for (int i = t; i < 64 * C2; i += 256) {
    int nn = i / C2, c2 = i % C2;
    ys[nn * 193 + c2] = ymax[((size_t)b * NN + n0 + nn) * C2 + c2];
  }
  for (int i = t; i < CC * C2; i += 256) {
    int o = i / C2, c2 = i % C2;       // w2[o][c2] row-major in global
    w2T[c2 * WTS + o] = w2[i];
  }
  __syncthreads();
  const int nn = t & 63;
  const int og = __builtin_amdgcn_readfirstlane(t >> 6);
  float acc[24];
  #pragma unroll
  for (int i = 0; i < 24; ++i) acc[i] = 0.f;
  const float* yrow = ys + nn * 193;
  for (int c2 = 0; c2 < C2; ++c2) {
    float yv = yrow[c2];
    const float* wp = &w2T[c2 * WTS + og * 24];  // 16B-aligned
    float4 w0 = *(const float4*)(wp);
    float4 w1 = *(const float4*)(wp + 4);
    float4 w2v = *(const float4*)(wp + 8);
    float4 w3 = *(const float4*)(wp + 12);
    float4 w4 = *(const float4*)(wp + 16);
    float4 w5 = *(const float4*)(wp + 20);
    const float wv[24] = {w0.x, w0.y, w0.z, w0.w, w1.x, w1.y, w1.z, w1.w,
                          w2v.x, w2v.y, w2v.z, w2v.w, w3.x, w3.y, w3.z, w3.w,
                          w4.x, w4.y, w4.z, w4.w, w5.x, w5.y, w5.z, w5.w};
    #pragma unroll
    for (int oi = 0; oi < 24; ++oi) acc[oi] = fmaf(wv[oi], yv, acc[oi]);
  }
  #pragma unroll
  for (int oi = 0; oi < 24; ++oi) {
    int o = og * 24 + oi;
    float g = bn2[o], be = bn2[CC + o], mn = bn2[2 * CC + o], vr = bn2[3 * CC + o];
    float inv = g / sqrtf(vr + 1e-5f);
    float v = fmaf(acc[oi] + b2[o], inv, be - mn * inv);
    size_t off = ((size_t)b * CC + o) * NN + n0 + nn;
    out[off] = v + xin[off];
  }
}

// ---------------------------------------------------------------------------
extern "C" void kernel_launch(void* const* d_in, const int* in_sizes, int n_in,
                              void* d_out, int out_size, void* d_ws, size_t ws_size,
                              hipStream_t stream) {
  const float* x     = (const float*)d_in[0];
  const float* fc1_w = (const float*)d_in[1];
  const float* fc1_b = (const float*)d_in[2];
  const float* bn1   = (const float*)d_in[3];
  const float* gc_w  = (const float*)d_in[4];
  const float* gc_b  = (const float*)d_in[5];
  const float* bng   = (const float*)d_in[6];
  const float* fc2_w = (const float*)d_in[7];
  const float* fc2_b = (const float*)d_in[8];
  const float* bn2   = (const float*)d_in[9];
  float* out = (float*)d_out;

  const size_t BNC = (size_t)BN_ * NN * CC;
  float* ws = (float*)d_ws;
  float* y1t = ws;                                   // B*N*C fp32
  unsigned short* xh = (unsigned short*)(y1t + BNC); // B*N*C bf16 hi
  unsigned short* xl = xh + BNC;                     // B*N*C bf16 lo
  float* sq     = ws + 2 * BNC;                      // B*N
  float* ymax   = sq + (size_t)BN_ * NN;             // B*N*C2 fp32
  int* nnidx = (int*)(ymax + (size_t)BN_ * NN * C2);

  // NCH=16 needs a dedicated cand_k region (14.45 MB) after nnidx; total
  // footprint 34.3 MB.  If ws is smaller, fall back to the verified NCH=8
  // layout with cand_k aliased onto ymax (7.2 MB <= 9.6 MB; cand_k is fully
  // consumed by k_nnmerge before k_gconv writes ymax -- single stream).
  const size_t base_bytes =
      (2 * BNC + (size_t)BN_ * NN + (size_t)BN_ * NN * C2) * 4 +
      (size_t)BN_ * NN * KNN * 4;                    // through nnidx
  const size_t need16 = base_bytes + (size_t)BN_ * 16 * NN * KNN * 8;
  int nch;
  uint64_t* cand_k;
  if (ws_size >= need16) {
    nch = 16;
    cand_k = (uint64_t*)((char*)d_ws + base_bytes);  // 8B-aligned (base%8==0)
  } else {
    nch = 8;
    cand_k = (uint64_t*)ymax;
  }

  k_fc1<<<dim3(NN / 64, BN_), 256, 0, stream>>>(x, fc1_w, fc1_b, bn1, y1t, xh, xl, sq);
  k_dist<<<dim3(NN / TILE, nch, BN_), 256, 0, stream>>>(xh, xl, sq, cand_k);
  k_nnmerge<<<dim3((BN_ * NN) / 64), 256, 0, stream>>>(cand_k, nnidx, nch);
  k_gconv<<<dim3((BN_ * NN) / PT), 256, 0, stream>>>(y1t, nnidx, gc_w, gc_b, bng, ymax);
  k_fc2<<<dim3(NN / 64, BN_), 256, 0, stream>>>(ymax, fc2_w, fc2_b, bn2, x, out);
}